// Round 14
// baseline (864.894 us; speedup 1.0000x reference)
//
#include <hip/hip_runtime.h>
#include <hip/hip_bf16.h>

#define NN 100000
#define EE 1600000
#define DD 128
#define SCAN_N (2 * NN)
#define SCAN_BLOCKS ((SCAN_N + 1023) / 1024)   // 196
#define FILL_PASSES 4
#define FILL_RANGE (NN / FILL_PASSES)          // 25000

typedef unsigned short u16;
typedef __attribute__((ext_vector_type(8))) short short8v;
typedef __attribute__((ext_vector_type(4))) float f32x4;

__device__ inline void bf16split(float v, u16& hi, u16& lo) {
    __hip_bfloat16 h = __float2bfloat16(v);          // RNE
    hi = *reinterpret_cast<u16*>(&h);
    float r = v - __bfloat162float(h);
    __hip_bfloat16 l = __float2bfloat16(r);
    lo = *reinterpret_cast<u16*>(&l);
}

// ---------------------------------------------------------------- prep
__global__ __launch_bounds__(256) void k_prep(const float* __restrict__ W1,
                                              const float* __restrict__ W2,
                                              const float* __restrict__ Wl1,
                                              const float* __restrict__ Wl2,
                                              u16* __restrict__ W1hi, u16* __restrict__ W1lo,
                                              u16* __restrict__ W2hi, u16* __restrict__ W2lo,
                                              u16* __restrict__ Wl1hi, u16* __restrict__ Wl1lo,
                                              u16* __restrict__ Wl2hi, u16* __restrict__ Wl2lo) {
    int tid = blockIdx.x * 256 + threadIdx.x;   // 131072 threads
    if (tid < 16384) {
        bf16split(W1[tid], W1hi[tid], W1lo[tid]);
    } else if (tid < 32768) {
        int i = tid - 16384;
        bf16split(W2[i], W2hi[i], W2lo[i]);
    } else if (tid < 98304) {
        int i = tid - 32768;                    // Wl1 [256][256]
        bf16split(Wl1[i], Wl1hi[i], Wl1lo[i]);
    } else {
        int i = tid - 98304;                    // Wl2 [128][256]
        bf16split(Wl2[i], Wl2hi[i], Wl2lo[i]);
    }
}

// ---------------------------------------------------------------- CSR build
__global__ __launch_bounds__(256) void k_count(const int* __restrict__ ei,
                                               int* __restrict__ off) {
    int e = blockIdx.x * 256 + threadIdx.x;
    int s = ei[e];
    int d = ei[EE + e];
    atomicAdd(&off[d], 1);
    atomicAdd(&off[NN + s], 1);
}

__global__ __launch_bounds__(256) void k_scan1(int* __restrict__ off,
                                               int* __restrict__ bsum) {
    __shared__ int s[256];
    int t = threadIdx.x;
    int base = blockIdx.x * 1024 + t * 4;
    int v[4];
    #pragma unroll
    for (int i = 0; i < 4; ++i) {
        int g = base + i;
        v[i] = (g < SCAN_N) ? off[g] : 0;
    }
    int local = v[0] + v[1] + v[2] + v[3];
    s[t] = local;
    __syncthreads();
    #pragma unroll
    for (int o = 1; o < 256; o <<= 1) {
        int add = (t >= o) ? s[t - o] : 0;
        __syncthreads();
        s[t] += add;
        __syncthreads();
    }
    int run = s[t] - local;
    #pragma unroll
    for (int i = 0; i < 4; ++i) {
        int g = base + i;
        if (g < SCAN_N) off[g] = run;
        run += v[i];
    }
    if (t == 0) bsum[blockIdx.x] = s[255];
}

__global__ __launch_bounds__(256) void k_scan2(int* __restrict__ bsum) {
    __shared__ int s[256];
    int t = threadIdx.x;
    int local = (t < SCAN_BLOCKS) ? bsum[t] : 0;
    s[t] = local;
    __syncthreads();
    #pragma unroll
    for (int o = 1; o < 256; o <<= 1) {
        int add = (t >= o) ? s[t - o] : 0;
        __syncthreads();
        s[t] += add;
        __syncthreads();
    }
    if (t < SCAN_BLOCKS) bsum[t] = s[t] - local;
}

__global__ __launch_bounds__(256) void k_scan3(int* __restrict__ off,
                                               const int* __restrict__ bsum,
                                               int* __restrict__ cur) {
    int t = threadIdx.x;
    int base = blockIdx.x * 1024 + t * 4;
    int add = bsum[blockIdx.x];
    #pragma unroll
    for (int i = 0; i < 4; ++i) {
        int g = base + i;
        if (g < SCAN_N) {
            int v = off[g] + add;
            off[g] = v;
            cur[g] = v;
        }
    }
    if (blockIdx.x == 0 && t == 0) off[SCAN_N] = 2 * EE;
}

__global__ __launch_bounds__(256) void k_fill(const int* __restrict__ ei,
                                              int* __restrict__ cur,
                                              int* __restrict__ idx) {
    int b = blockIdx.x;
    int w = b >> 3, myk = b & 7;
    int e = w * 256 + threadIdx.x;
    int s = ei[e];
    int d = ei[EE + e];
    bool ownD = (((d >> 3) & 7) == myk);
    bool ownS = (((s >> 3) & 7) == myk);
    #pragma unroll
    for (int p = 0; p < FILL_PASSES; ++p) {
        if (ownD && d >= p * FILL_RANGE && d < (p + 1) * FILL_RANGE) {
            int p1 = atomicAdd(&cur[d], 1);
            idx[p1] = s;
        }
        if (ownS && s >= p * FILL_RANGE && s < (p + 1) * FILL_RANGE) {
            int p2 = atomicAdd(&cur[NN + s], 1);
            idx[p2] = d;
        }
        __syncthreads();
    }
}

// ---------------------------------------------------------------- gather
// Unroll 4 (unroll-8 regressed: VGPR 32, occupancy down; BW-bound kernel).
// NT loads for idx (read-once stream), NT stores for h1/h2 (write-once,
// consumed in a later dispatch) -- keeps x L3-resident so its ~32x logical
// re-reads get cache-served (round-11 FETCH was 799MB vs 51MB x working set).
// NT store via clang ext_vector f32x4 (HIP float4 class type is rejected by
// the builtin -- round-12 compile fail).
__global__ __launch_bounds__(256) void k_gather(const float4* __restrict__ x4,
                                                const int* __restrict__ off,
                                                const int* __restrict__ idx,
                                                float4* __restrict__ h1,
                                                float4* __restrict__ h2) {
    int t = threadIdx.x;
    int g = blockIdx.x * 8 + (t >> 5);
    int c = t & 31;
    int n = (g < NN) ? g : g - NN;
    int o0 = off[g], o1 = off[g + 1];
    float4 acc = x4[n * 32 + c];
    int j = o0;
    for (; j + 4 <= o1; j += 4) {
        int n0 = __builtin_nontemporal_load(&idx[j + 0]);
        int n1 = __builtin_nontemporal_load(&idx[j + 1]);
        int n2 = __builtin_nontemporal_load(&idx[j + 2]);
        int n3 = __builtin_nontemporal_load(&idx[j + 3]);
        float4 v0 = x4[n0 * 32 + c];
        float4 v1 = x4[n1 * 32 + c];
        float4 v2 = x4[n2 * 32 + c];
        float4 v3 = x4[n3 * 32 + c];
        acc.x += v0.x + v1.x + v2.x + v3.x;
        acc.y += v0.y + v1.y + v2.y + v3.y;
        acc.z += v0.z + v1.z + v2.z + v3.z;
        acc.w += v0.w + v1.w + v2.w + v3.w;
    }
    for (; j < o1; ++j) {
        int nbr = __builtin_nontemporal_load(&idx[j]);
        float4 v = x4[nbr * 32 + c];
        acc.x += v.x; acc.y += v.y; acc.z += v.z; acc.w += v.w;
    }
    float4* hout = (g < NN) ? &h1[n * 32 + c] : &h2[n * 32 + c];
    f32x4 av = {acc.x, acc.y, acc.z, acc.w};
    __builtin_nontemporal_store(av, (f32x4*)hout);
}

// ---------------------------------------------------------------- branch (MFMA)
__global__ __launch_bounds__(256, 2) void k_branch_mfma(const float* __restrict__ h1,
                                                        const float* __restrict__ h2,
                                                        const u16* __restrict__ W1hi,
                                                        const u16* __restrict__ W1lo,
                                                        const u16* __restrict__ W2hi,
                                                        const u16* __restrict__ W2lo,
                                                        const float* __restrict__ bias1,
                                                        const float* __restrict__ bias2,
                                                        const float* __restrict__ gam1,
                                                        const float* __restrict__ gam2,
                                                        const float* __restrict__ beta1,
                                                        const float* __restrict__ beta2,
                                                        float* __restrict__ cat) {
    const int br = blockIdx.y;
    const float* h    = br ? h2    : h1;
    const u16*  Whi   = br ? W2hi  : W1hi;
    const u16*  Wlo   = br ? W2lo  : W1lo;
    const float* bias = br ? bias2 : bias1;
    const float* gam  = br ? gam2  : gam1;
    const float* beta = br ? beta2 : beta1;
    const int colOff  = br ? 128 : 0;

    __shared__ u16 ahi[128 * 40], alo[128 * 40], bhi[128 * 40], blo[128 * 40];
    __shared__ float red[2][128][2];            // [wn][row][s,q]
    int t = threadIdx.x;
    int m0 = blockIdx.x * 128;
    int lane = t & 63, wid = t >> 6;
    int wm = wid >> 1, wn = wid & 1;
    int lr = lane & 15, lg = lane >> 4;

    f32x4 acc[4][4];
    #pragma unroll
    for (int i = 0; i < 4; ++i)
        #pragma unroll
        for (int j = 0; j < 4; ++j) acc[i][j] = (f32x4){0.f, 0.f, 0.f, 0.f};

    for (int k0 = 0; k0 < 128; k0 += 32) {
        __syncthreads();
        #pragma unroll
        for (int it = 0; it < 4; ++it) {
            int f = it * 256 + t;
            int m = f >> 3, q = f & 7;
            int node = m0 + m;
            float4 v = make_float4(0.f, 0.f, 0.f, 0.f);
            if (node < NN) v = ((const float4*)h)[(size_t)node * 32 + (k0 >> 2) + q];
            u16 h0, l0, h1_, l1_, h2_, l2_, h3, l3;
            bf16split(v.x, h0, l0);
            bf16split(v.y, h1_, l1_);
            bf16split(v.z, h2_, l2_);
            bf16split(v.w, h3, l3);
            uint* ph = (uint*)&ahi[m * 40 + q * 4];
            ph[0] = (uint)h0 | ((uint)h1_ << 16);
            ph[1] = (uint)h2_ | ((uint)h3 << 16);
            uint* pl = (uint*)&alo[m * 40 + q * 4];
            pl[0] = (uint)l0 | ((uint)l1_ << 16);
            pl[1] = (uint)l2_ | ((uint)l3 << 16);
        }
        #pragma unroll
        for (int it = 0; it < 2; ++it) {
            int f = it * 256 + t;
            int n = f >> 2, q = f & 3;
            int gsrc = n * 128 + k0 + q * 8;
            *(uint4*)&bhi[n * 40 + q * 8] = *(const uint4*)&Whi[gsrc];
            *(uint4*)&blo[n * 40 + q * 8] = *(const uint4*)&Wlo[gsrc];
        }
        __syncthreads();

        short8v afh[4], afl[4];
        #pragma unroll
        for (int mt = 0; mt < 4; ++mt) {
            int r = wm * 64 + mt * 16 + lr;
            afh[mt] = *(const short8v*)&ahi[r * 40 + lg * 8];
            afl[mt] = *(const short8v*)&alo[r * 40 + lg * 8];
        }
        #pragma unroll
        for (int nt = 0; nt < 4; ++nt) {
            int c = wn * 64 + nt * 16 + lr;
            short8v bfh = *(const short8v*)&bhi[c * 40 + lg * 8];
            short8v bfl = *(const short8v*)&blo[c * 40 + lg * 8];
            #pragma unroll
            for (int mt = 0; mt < 4; ++mt) {
                acc[mt][nt] = __builtin_amdgcn_mfma_f32_16x16x32_bf16(afh[mt], bfh, acc[mt][nt], 0, 0, 0);
                acc[mt][nt] = __builtin_amdgcn_mfma_f32_16x16x32_bf16(afh[mt], bfl, acc[mt][nt], 0, 0, 0);
                acc[mt][nt] = __builtin_amdgcn_mfma_f32_16x16x32_bf16(afl[mt], bfh, acc[mt][nt], 0, 0, 0);
            }
        }
    }

    float breg[4], greg[4], btreg[4];
    #pragma unroll
    for (int nt = 0; nt < 4; ++nt) {
        int col = wn * 64 + nt * 16 + lr;
        breg[nt]  = bias[col];
        greg[nt]  = gam[col];
        btreg[nt] = beta[col];
    }
    #pragma unroll
    for (int mt = 0; mt < 4; ++mt)
        #pragma unroll
        for (int nt = 0; nt < 4; ++nt)
            #pragma unroll
            for (int r = 0; r < 4; ++r) acc[mt][nt][r] += breg[nt];

    #pragma unroll
    for (int mt = 0; mt < 4; ++mt) {
        #pragma unroll
        for (int r = 0; r < 4; ++r) {
            float s = 0.f, q = 0.f;
            #pragma unroll
            for (int nt = 0; nt < 4; ++nt) {
                float v = acc[mt][nt][r];
                s += v;
                q += v * v;
            }
            #pragma unroll
            for (int o = 1; o < 16; o <<= 1) {
                s += __shfl_xor(s, o);
                q += __shfl_xor(q, o);
            }
            if (lr == 0) {
                int row = wm * 64 + mt * 16 + lg * 4 + r;
                red[wn][row][0] = s;
                red[wn][row][1] = q;
            }
        }
    }
    __syncthreads();

    #pragma unroll
    for (int mt = 0; mt < 4; ++mt) {
        #pragma unroll
        for (int r = 0; r < 4; ++r) {
            int row = wm * 64 + mt * 16 + lg * 4 + r;
            int node = m0 + row;
            float s = red[0][row][0] + red[1][row][0];
            float q = red[0][row][1] + red[1][row][1];
            float mu  = s * (1.f / 128.f);
            float var = q * (1.f / 128.f) - mu * mu;
            float rs  = rsqrtf(var + 1e-5f);
            if (node < NN) {
                const float* hrow = &h[(size_t)node * 128];
                #pragma unroll
                for (int nt = 0; nt < 4; ++nt) {
                    int col = wn * 64 + nt * 16 + lr;
                    float y = (acc[mt][nt][r] - mu) * rs * greg[nt] + btreg[nt];
                    float o_ = hrow[col] + fmaxf(y, 0.f);
                    cat[(size_t)node * 256 + colOff + col] = o_;
                }
            }
        }
    }
}

// ---------------------------------------------------------------- MFMA MLP
__global__ __launch_bounds__(256, 2) void k_mfma_mlp(const float* __restrict__ A,
                                                     const u16* __restrict__ Bhi,
                                                     const u16* __restrict__ Blo,
                                                     const float* __restrict__ bias,
                                                     float* __restrict__ C,
                                                     int ldC) {
    __shared__ u16 ahi[128 * 40], alo[128 * 40], bhi[128 * 40], blo[128 * 40];
    int t = threadIdx.x;
    int m0 = blockIdx.x * 128;
    int nbase = blockIdx.y * 128;
    int lane = t & 63, wid = t >> 6;
    int wm = wid >> 1, wn = wid & 1;
    int lr = lane & 15, lg = lane >> 4;

    f32x4 acc[4][4];
    #pragma unroll
    for (int i = 0; i < 4; ++i)
        #pragma unroll
        for (int j = 0; j < 4; ++j) acc[i][j] = (f32x4){0.f, 0.f, 0.f, 0.f};

    for (int k0 = 0; k0 < 256; k0 += 32) {
        __syncthreads();
        #pragma unroll
        for (int it = 0; it < 4; ++it) {
            int f = it * 256 + t;
            int m = f >> 3, q = f & 7;
            int node = m0 + m;
            float4 v = make_float4(0.f, 0.f, 0.f, 0.f);
            if (node < NN) v = ((const float4*)A)[(size_t)node * 64 + (k0 >> 2) + q];
            u16 h0, l0, h1_, l1_, h2_, l2_, h3, l3;
            bf16split(v.x, h0, l0);
            bf16split(v.y, h1_, l1_);
            bf16split(v.z, h2_, l2_);
            bf16split(v.w, h3, l3);
            uint* ph = (uint*)&ahi[m * 40 + q * 4];
            ph[0] = (uint)h0 | ((uint)h1_ << 16);
            ph[1] = (uint)h2_ | ((uint)h3 << 16);
            uint* pl = (uint*)&alo[m * 40 + q * 4];
            pl[0] = (uint)l0 | ((uint)l1_ << 16);
            pl[1] = (uint)l2_ | ((uint)l3 << 16);
        }
        #pragma unroll
        for (int it = 0; it < 2; ++it) {
            int f = it * 256 + t;
            int n = f >> 2, q = f & 3;
            size_t gsrc = (size_t)(nbase + n) * 256 + k0 + q * 8;
            *(uint4*)&bhi[n * 40 + q * 8] = *(const uint4*)&Bhi[gsrc];
            *(uint4*)&blo[n * 40 + q * 8] = *(const uint4*)&Blo[gsrc];
        }
        __syncthreads();

        short8v afh[4], afl[4];
        #pragma unroll
        for (int mt = 0; mt < 4; ++mt) {
            int r = wm * 64 + mt * 16 + lr;
            afh[mt] = *(const short8v*)&ahi[r * 40 + lg * 8];
            afl[mt] = *(const short8v*)&alo[r * 40 + lg * 8];
        }
        #pragma unroll
        for (int nt = 0; nt < 4; ++nt) {
            int c = wn * 64 + nt * 16 + lr;
            short8v bfh = *(const short8v*)&bhi[c * 40 + lg * 8];
            short8v bfl = *(const short8v*)&blo[c * 40 + lg * 8];
            #pragma unroll
            for (int mt = 0; mt < 4; ++mt) {
                acc[mt][nt] = __builtin_amdgcn_mfma_f32_16x16x32_bf16(afh[mt], bfh, acc[mt][nt], 0, 0, 0);
                acc[mt][nt] = __builtin_amdgcn_mfma_f32_16x16x32_bf16(afh[mt], bfl, acc[mt][nt], 0, 0, 0);
                acc[mt][nt] = __builtin_amdgcn_mfma_f32_16x16x32_bf16(afl[mt], bfh, acc[mt][nt], 0, 0, 0);
            }
        }
    }

    #pragma unroll
    for (int nt = 0; nt < 4; ++nt) {
        int col = nbase + wn * 64 + nt * 16 + lr;
        float bv = bias[col];
        #pragma unroll
        for (int mt = 0; mt < 4; ++mt) {
            #pragma unroll
            for (int r = 0; r < 4; ++r) {
                int row = m0 + wm * 64 + mt * 16 + lg * 4 + r;
                if (row < NN) {
                    float v = fmaxf(acc[mt][nt][r] + bv, 0.f);
                    C[(size_t)row * ldC + col] = v;
                }
            }
        }
    }
}

// ---------------------------------------------------------------- launch
extern "C" void kernel_launch(void* const* d_in, const int* in_sizes, int n_in,
                              void* d_out, int out_size, void* d_ws, size_t ws_size,
                              hipStream_t stream) {
    const float* x   = (const float*)d_in[0];
    const int*   ei  = (const int*)d_in[1];
    const float* W1  = (const float*)d_in[2];
    const float* b1  = (const float*)d_in[3];
    const float* g1  = (const float*)d_in[4];
    const float* bt1 = (const float*)d_in[5];
    const float* W2  = (const float*)d_in[6];
    const float* b2  = (const float*)d_in[7];
    const float* g2  = (const float*)d_in[8];
    const float* bt2 = (const float*)d_in[9];
    const float* Wl1 = (const float*)d_in[10];
    const float* bl1 = (const float*)d_in[11];
    const float* Wl2 = (const float*)d_in[12];
    const float* bl2 = (const float*)d_in[13];
    float* out = (float*)d_out;

    float* ws    = (float*)d_ws;
    float* h1    = ws;
    float* h2    = ws + (size_t)NN * DD;
    float* mid   = ws;                          // reuse h region after branches
    float* cat   = ws + (size_t)2 * NN * DD;
    u16*   W1hi  = (u16*)(ws + (size_t)4 * NN * DD);
    u16*   W1lo  = W1hi + 16384;
    u16*   W2hi  = W1lo + 16384;
    u16*   W2lo  = W2hi + 16384;
    u16*   Wl1hi = W2lo + 16384;
    u16*   Wl1lo = Wl1hi + 65536;
    u16*   Wl2hi = Wl1lo + 65536;
    u16*   Wl2lo = Wl2hi + 32768;
    int*   off   = (int*)(Wl2lo + 32768);
    int*   cur   = off + SCAN_N + 1;
    int*   idx   = cur + SCAN_N;
    int*   bsum  = idx + 2 * EE;

    k_prep<<<512, 256, 0, stream>>>(W1, W2, Wl1, Wl2,
                                    W1hi, W1lo, W2hi, W2lo,
                                    Wl1hi, Wl1lo, Wl2hi, Wl2lo);

    hipMemsetAsync(off, 0, (SCAN_N + 1) * sizeof(int), stream);
    k_count<<<EE / 256, 256, 0, stream>>>(ei, off);
    k_scan1<<<SCAN_BLOCKS, 256, 0, stream>>>(off, bsum);
    k_scan2<<<1, 256, 0, stream>>>(bsum);
    k_scan3<<<SCAN_BLOCKS, 256, 0, stream>>>(off, bsum, cur);
    k_fill<<<(EE / 256) * 8, 256, 0, stream>>>(ei, cur, idx);

    k_gather<<<SCAN_N / 8, 256, 0, stream>>>((const float4*)x, off, idx,
                                             (float4*)h1, (float4*)h2);

    int nb128 = (NN + 127) / 128;
    k_branch_mfma<<<dim3(nb128, 2), 256, 0, stream>>>(h1, h2,
                                                      W1hi, W1lo, W2hi, W2lo,
                                                      b1, b2, g1, g2, bt1, bt2, cat);

    k_mfma_mlp<<<dim3(nb128, 2), 256, 0, stream>>>(cat, Wl1hi, Wl1lo, bl1, mid, 256);
    k_mfma_mlp<<<dim3(nb128, 1), 256, 0, stream>>>(mid, Wl2hi, Wl2lo, bl2, out, 128);
}